// Round 1
// 209.334 us; speedup vs baseline: 1.0690x; 1.0690x over previous
//
#include <hip/hip_runtime.h>
#include <stdint.h>

#define N_TOK  16384
#define EMB    512
#define NEMB   2048
#define NCHUNK 32            // 64 templates per chunk
#define CWIN   2.5e-4f       // ref-f32-grid + bf16 score-noise margin (passed R5-R7)
#define WCAP   524288

typedef __attribute__((ext_vector_type(8))) short s16x8;
typedef __attribute__((ext_vector_type(4))) float f32x4;

__device__ __forceinline__ unsigned short f2bf(float f) {   // RNE f32 -> bf16
  unsigned u = __float_as_uint(f);
  u += 0x7fffu + ((u >> 16) & 1u);
  return (unsigned short)(u >> 16);
}
// monotone f32 -> u32 (total order, NaN sorts above all reals)
__device__ __forceinline__ unsigned mapf(float f) {
  unsigned u = __float_as_uint(f);
  return (u >> 31) ? ~u : (u | 0x80000000u);
}
__device__ __forceinline__ float unmapf(unsigned u) {
  return __uint_as_float((u >> 31) ? (u & 0x7fffffffu) : ~u);
}

// numpy pairwise_sum emulation for sum(x*x) over 512 contiguous f32.
__device__ __forceinline__ float pairwise512_sq(const float* se, int lane) {
  int l = lane & 31;
  int b = l >> 3, j = l & 7;
  const float* base = se + b * 128 + j;
  float x = base[0];
  float r = __fmul_rn(x, x);
#pragma unroll
  for (int k = 1; k < 16; ++k) {
    float y = base[8 * k];
    r = __fadd_rn(r, __fmul_rn(y, y));
  }
  r = __fadd_rn(r, __shfl_xor(r, 1));
  r = __fadd_rn(r, __shfl_xor(r, 2));
  r = __fadd_rn(r, __shfl_xor(r, 4));
  r = __fadd_rn(r, __shfl_xor(r, 8));
  r = __fadd_rn(r, __shfl_xor(r, 16));
  return r;
}

// ---------- kernel 1: fused prep, 4 rows per block (wave per row) ----------
__global__ __launch_bounds__(256) void prep_kernel(
    const float* __restrict__ tmp, const float* __restrict__ enc,
    unsigned short* __restrict__ thi, float* __restrict__ tsq,
    unsigned short* __restrict__ ehi, float* __restrict__ esq,
    int* __restrict__ wcount) {
  __shared__ float se[4][EMB];
  int wv = threadIdx.x >> 6, lane = threadIdx.x & 63;
  int row = blockIdx.x * 4 + wv;                             // 18432 rows
  if (blockIdx.x == 0 && threadIdx.x == 0) *wcount = 0;
  bool isT = row < NEMB;
  const float* src = isT ? (tmp + (size_t)row * EMB)
                         : (enc + (size_t)(row - NEMB) * EMB);
  const float4* p = (const float4*)src + lane * 2;
  float4 v0 = p[0], v1 = p[1];
  float f[8] = {v0.x, v0.y, v0.z, v0.w, v1.x, v1.y, v1.z, v1.w};
  unsigned h[8];
#pragma unroll
  for (int i = 0; i < 8; ++i) { h[i] = f2bf(f[i]); se[wv][lane * 8 + i] = f[i]; }
  uint4 packed = { h[0] | (h[1] << 16), h[2] | (h[3] << 16),
                   h[4] | (h[5] << 16), h[6] | (h[7] << 16) };
  unsigned short* dsth = isT ? (thi + (size_t)row * EMB)
                             : (ehi + (size_t)(row - NEMB) * EMB);
  ((uint4*)dsth)[lane] = packed;
  __syncthreads();
  float s = pairwise512_sq(se[wv], lane);
  if (lane == 0) { if (isT) tsq[row] = s; else esq[row - NEMB] = s; }
}

// ---------- kernel 2: 256x256-tile 8-wave phased GEMM (T2+T3+T4+T5) ----------
// grid 512: tokb = bid>>3 (256 tokens), nb = bid&7 (256 templates = 4 chunks).
// K = 512 = 8 K-tiles of BK=64; each K-tile = two 32-wide kk panels.
// LDS 128 KiB: A[buf][kk] panels (256 rows x 32 bf16 = 16 KB) at (buf*2+kk)*16384,
//              B panels same at +65536.  st_16x32 swizzle: phys = P ^ ((P>>9&1)<<5),
//              applied via inverse-swizzled GLOBAL source (linear global_load_lds dest)
//              + swizzled ds_read address (both-sides-or-neither rule).
// Stage schedule (1 panel / phase, 4 phases / K-tile, units in vmcnt order):
//   A-kk0(kt)@g3(kt-2)  B-kk0(kt)@g4(kt-2)  A-kk1(kt)@g1(kt-1)  B-kk1(kt)@g2(kt-1)
// Waits (before end-of-phase barrier; per-wave vmcnt + barrier = collective):
//   end g2(kt): protects kk1(kt) reads at g3: 4 units newer -> vmcnt(8)   [kt==7: 0]
//   end g4(kt): protects kk0(kt+1) reads at g1: 4 units newer -> vmcnt(8) [kt==6: 4]
// MFMA order per acc element: kt ascending, kk0 then kk1 -> scores BIT-IDENTICAL
// to the previous (passing) kernel; downstream CWIN/refine logic unchanged.
__global__ __launch_bounds__(512, 2) void score_kernel(
    const unsigned short* __restrict__ ehi, const unsigned short* __restrict__ thi,
    const float* __restrict__ tsq,
    unsigned long long* __restrict__ keyc, unsigned* __restrict__ s2c) {
  __shared__ __align__(16) char smem[131072];
  const int tid = threadIdx.x, w = tid >> 6, lane = tid & 63;
  const int q = lane >> 4, r = lane & 15;
  const int wr = w >> 2, wc = w & 3;               // 2M x 4N wave grid
  const int tokb = (int)blockIdx.x >> 3;           // 64
  const int nb   = (int)blockIdx.x & 7;            // 8

  // ---- per-thread stage-source precompute (inverse swizzle of linear dest) ----
  const int c0 = tid, c1 = 512 + tid;
  const int L0 = (c0 * 16) ^ ((((c0 * 16) >> 9) & 1) << 5);
  const int L1 = (c1 * 16) ^ ((((c1 * 16) >> 9) & 1) << 5);
  const int row0 = L0 >> 6, ce0 = (L0 & 63) >> 1;
  const int row1 = L1 >> 6, ce1 = (L1 & 63) >> 1;
  const unsigned short* pa0 = ehi + (size_t)(tokb * 256 + row0) * EMB + ce0;
  const unsigned short* pa1 = ehi + (size_t)(tokb * 256 + row1) * EMB + ce1;
  const unsigned short* pb0 = thi + (size_t)(nb  * 256 + row0) * EMB + ce0;
  const unsigned short* pb1 = thi + (size_t)(nb  * 256 + row1) * EMB + ce1;

#define STAGE_A(ktp, kk) do {                                                     \
    char* lb_ = smem + ((((ktp) & 1) * 2 + (kk)) << 14) + (w << 10);              \
    __builtin_amdgcn_global_load_lds(                                             \
        (const __attribute__((address_space(1))) void*)(pa0 + (ktp) * 64 + (kk) * 32), \
        (__attribute__((address_space(3))) void*)lb_, 16, 0, 0);                  \
    __builtin_amdgcn_global_load_lds(                                             \
        (const __attribute__((address_space(1))) void*)(pa1 + (ktp) * 64 + (kk) * 32), \
        (__attribute__((address_space(3))) void*)(lb_ + 8192), 16, 0, 0);         \
  } while (0)
#define STAGE_B(ktp, kk) do {                                                     \
    char* lb_ = smem + 65536 + ((((ktp) & 1) * 2 + (kk)) << 14) + (w << 10);      \
    __builtin_amdgcn_global_load_lds(                                             \
        (const __attribute__((address_space(1))) void*)(pb0 + (ktp) * 64 + (kk) * 32), \
        (__attribute__((address_space(3))) void*)lb_, 16, 0, 0);                  \
    __builtin_amdgcn_global_load_lds(                                             \
        (const __attribute__((address_space(1))) void*)(pb1 + (ktp) * 64 + (kk) * 32), \
        (__attribute__((address_space(3))) void*)(lb_ + 8192), 16, 0, 0);         \
  } while (0)

  // ---- swizzled fragment-read offsets (within a 16 KB panel) ----
  int offA[8], offB[4];
#pragma unroll
  for (int m = 0; m < 8; ++m) {
    int P = (wr * 128 + m * 16 + r) * 64 + q * 16;
    offA[m] = P ^ (((P >> 9) & 1) << 5);
  }
#pragma unroll
  for (int n = 0; n < 4; ++n) {
    int P = (wc * 64 + n * 16 + r) * 64 + q * 16;
    offB[n] = P ^ (((P >> 9) & 1) << 5);
  }

  f32x4 acc[8][4];
#pragma unroll
  for (int m = 0; m < 8; ++m)
#pragma unroll
    for (int n = 0; n < 4; ++n) acc[m][n] = (f32x4){0.f, 0.f, 0.f, 0.f};

  // ---- prologue: kt0 all 4 panels + kt1 kk0 panels (units #1..#6) ----
  STAGE_A(0, 0); STAGE_B(0, 0); STAGE_A(0, 1); STAGE_B(0, 1); STAGE_A(1, 0); STAGE_B(1, 0);
  asm volatile("s_waitcnt vmcnt(8)" ::: "memory");   // units 1,2 (kk0 of kt0) landed
  __builtin_amdgcn_s_barrier();

#define LOADA(kkbase, mh)                                        \
    a0 = *(const s16x8*)(Ab_ + (kkbase) + offA[(mh) * 4 + 0]);   \
    a1 = *(const s16x8*)(Ab_ + (kkbase) + offA[(mh) * 4 + 1]);   \
    a2 = *(const s16x8*)(Ab_ + (kkbase) + offA[(mh) * 4 + 2]);   \
    a3 = *(const s16x8*)(Ab_ + (kkbase) + offA[(mh) * 4 + 3]);
#define LOADB(kkbase)                                            \
    bf4[0] = *(const s16x8*)(Bb_ + (kkbase) + offB[0]);          \
    bf4[1] = *(const s16x8*)(Bb_ + (kkbase) + offB[1]);          \
    bf4[2] = *(const s16x8*)(Bb_ + (kkbase) + offB[2]);          \
    bf4[3] = *(const s16x8*)(Bb_ + (kkbase) + offB[3]);
#define MFMA_HALF(mh)                                                              \
    __builtin_amdgcn_s_setprio(1);                                                 \
    _Pragma("unroll")                                                              \
    for (int n = 0; n < 4; ++n) {                                                  \
      acc[(mh) * 4 + 0][n] = __builtin_amdgcn_mfma_f32_16x16x32_bf16(a0, bf4[n], acc[(mh) * 4 + 0][n], 0, 0, 0); \
      acc[(mh) * 4 + 1][n] = __builtin_amdgcn_mfma_f32_16x16x32_bf16(a1, bf4[n], acc[(mh) * 4 + 1][n], 0, 0, 0); \
      acc[(mh) * 4 + 2][n] = __builtin_amdgcn_mfma_f32_16x16x32_bf16(a2, bf4[n], acc[(mh) * 4 + 2][n], 0, 0, 0); \
      acc[(mh) * 4 + 3][n] = __builtin_amdgcn_mfma_f32_16x16x32_bf16(a3, bf4[n], acc[(mh) * 4 + 3][n], 0, 0, 0); \
    }                                                                              \
    __builtin_amdgcn_s_setprio(0);

#pragma unroll
  for (int kt = 0; kt < 8; ++kt) {
    char* Ab_ = smem + ((kt & 1) * 2 << 14);
    char* Bb_ = smem + 65536 + ((kt & 1) * 2 << 14);
    s16x8 a0, a1, a2, a3, bf4[4];
    // -- g1: kk0, m0-3; stage A-kk1(kt+1)
    LOADA(0, 0); LOADB(0);
    if (kt + 1 < 8) STAGE_A(kt + 1, 1);
    __builtin_amdgcn_s_barrier();
    MFMA_HALF(0);
    __builtin_amdgcn_s_barrier();
    // -- g2: kk0, m4-7; stage B-kk1(kt+1); wait for kk1(kt)
    LOADA(0, 1);
    if (kt + 1 < 8) STAGE_B(kt + 1, 1);
    __builtin_amdgcn_s_barrier();
    MFMA_HALF(1);
    if (kt < 7) { asm volatile("s_waitcnt vmcnt(8)" ::: "memory"); }
    else        { asm volatile("s_waitcnt vmcnt(0)" ::: "memory"); }
    __builtin_amdgcn_s_barrier();
    // -- g3: kk1, m0-3; stage A-kk0(kt+2)
    LOADA(16384, 0); LOADB(16384);
    if (kt + 2 < 8) STAGE_A(kt + 2, 0);
    __builtin_amdgcn_s_barrier();
    MFMA_HALF(0);
    __builtin_amdgcn_s_barrier();
    // -- g4: kk1, m4-7; stage B-kk0(kt+2); wait for kk0(kt+1)
    LOADA(16384, 1);
    if (kt + 2 < 8) STAGE_B(kt + 2, 0);
    __builtin_amdgcn_s_barrier();
    MFMA_HALF(1);
    if (kt < 6)       { asm volatile("s_waitcnt vmcnt(8)" ::: "memory"); }
    else if (kt == 6) { asm volatile("s_waitcnt vmcnt(4)" ::: "memory"); }
    __builtin_amdgcn_s_barrier();
  }

  // ---- epilogue: in-register argmin; wave (wr,wc) owns tokens wr*128..+127
  // of chunk nb*4+wc. Butterfly over r (16 template cols per fragment).
  const int chunk = nb * 4 + wc;
  const int nbase = nb * 256 + wc * 64;
  float tq[4];
#pragma unroll
  for (int n = 0; n < 4; ++n) tq[n] = tsq[nbase + n * 16 + r];
#pragma unroll
  for (int m = 0; m < 8; ++m) {
#pragma unroll
    for (int i = 0; i < 4; ++i) {
      unsigned long long k1 = ~0ULL; unsigned s2m = 0xffffffffu;
#pragma unroll
      for (int n = 0; n < 4; ++n) {                 // n ascending = template ascending
        float s = tq[n] - 2.0f * acc[m][n][i];
        unsigned sm = mapf(s);
        unsigned long long k =
            ((unsigned long long)sm << 32) | (unsigned)(nbase + n * 16 + r);
        if (k < k1) { unsigned o = (unsigned)(k1 >> 32); s2m = o < s2m ? o : s2m; k1 = k; }
        else s2m = sm < s2m ? sm : s2m;
      }
#pragma unroll
      for (int mask = 1; mask < 16; mask <<= 1) {
        unsigned long long ok = __shfl_xor(k1, mask);
        unsigned os = __shfl_xor(s2m, mask);
        if (ok < k1) { unsigned o = (unsigned)(k1 >> 32); s2m = o < s2m ? o : s2m; k1 = ok; }
        else { unsigned o = (unsigned)(ok >> 32); s2m = o < s2m ? o : s2m; }
        s2m = os < s2m ? os : s2m;
      }
      if (r == 0) {
        int token = tokb * 256 + wr * 128 + m * 16 + q * 4 + i;
        keyc[(size_t)chunk * N_TOK + token] = k1;
        s2c [(size_t)chunk * N_TOK + token] = s2m;
      }
    }
  }
#undef STAGE_A
#undef STAGE_B
#undef LOADA
#undef LOADB
#undef MFMA_HALF
}

// ---------- kernel 3: 32-way key merge, flag, worklist; inits rkey ----------
__global__ __launch_bounds__(64) void merge_kernel(
    const unsigned long long* __restrict__ keyc, const unsigned* __restrict__ s2c,
    int* __restrict__ bestIdx, int* __restrict__ flag, int* __restrict__ work,
    int* __restrict__ wcount, unsigned long long* __restrict__ rkey) {
  int t = blockIdx.x * 64 + threadIdx.x;
  if (t >= N_TOK) return;
  rkey[t] = ~0ULL;
  unsigned long long K = ~0ULL; unsigned S = 0xffffffffu;
  for (int c = 0; c < NCHUNK; ++c) {
    unsigned long long k = keyc[(size_t)c * N_TOK + t];
    unsigned s2 = s2c[(size_t)c * N_TOK + t];
    if (k < K) { unsigned o = (unsigned)(K >> 32); S = o < S ? o : S; K = k; }
    else { unsigned o = (unsigned)(k >> 32); S = o < S ? o : S; }
    S = s2 < S ? s2 : S;
  }
  float best_f   = unmapf((unsigned)(K >> 32));
  float second_f = unmapf(S);
  int idx = (int)(unsigned)(K & 0xffffffffu);
  bestIdx[t] = idx;
  bool ok = (second_f - best_f >= CWIN) && (idx >= 0) && (idx < NEMB) && (best_f == best_f);
  flag[t] = ok ? 0 : 1;
  if (!ok) {
    bool nanCase = !(best_f == best_f);
    float limit = best_f + CWIN;
    for (int c = 0; c < NCHUNK; ++c) {
      float cf = unmapf((unsigned)(keyc[(size_t)c * N_TOK + t] >> 32));
      if (nanCase || !(cf > limit)) {               // NaN-safe candidate test
        int pos = atomicAdd(wcount, 1);
        if (pos < WCAP) work[pos] = t * NCHUNK + c;
      }
    }
  }
}

// ---------- kernel 4: coalesced f32-emulated rescan over worklist pairs ----------
__global__ __launch_bounds__(256) void refine_kernel(
    const float* __restrict__ enc, const float* __restrict__ tmp,
    const float* __restrict__ esq, const float* __restrict__ tsq,
    const int* __restrict__ work, const int* __restrict__ wcount,
    unsigned long long* __restrict__ rkey) {
  int total = *wcount; if (total > WCAP) total = WCAP;
  __shared__ float se[EMB];
  const int wv = threadIdx.x >> 6, lane = threadIdx.x & 63;
  for (int p = blockIdx.x; p < total; p += gridDim.x) {
    __syncthreads();
    int item = work[p];
    int token = item / NCHUNK, c = item % NCHUNK;
    const float4* erow = (const float4*)(enc + (size_t)token * EMB);
    for (int i = threadIdx.x; i < 128; i += 256) ((float4*)se)[i] = erow[i];
    __syncthreads();
    float e2 = esq[token];
    unsigned long long lkey = ~0ULL;
#pragma unroll
    for (int j = 0; j < 16; ++j) {
      int m = c * 64 + wv + j * 4;
      const float4* trow = (const float4*)(tmp + (size_t)m * EMB);
      float4 a0 = trow[lane], a1 = trow[lane + 64];
      float4 b0 = ((const float4*)se)[lane], b1 = ((const float4*)se)[lane + 64];
      double s = (double)a0.x * b0.x + (double)a0.y * b0.y
               + (double)a0.z * b0.z + (double)a0.w * b0.w
               + (double)a1.x * b1.x + (double)a1.y * b1.y
               + (double)a1.z * b1.z + (double)a1.w * b1.w;
#pragma unroll
      for (int mask = 1; mask < 64; mask <<= 1) s += __shfl_xor(s, mask);
      if (lane == 0) {
        float M  = (float)s;
        float d1 = __fadd_rn(e2, -__fmul_rn(2.0f, M));
        float d2 = __fadd_rn(d1, tsq[m]);            // full dist >= 0: bits monotone
        unsigned long long key =
            ((unsigned long long)__float_as_uint(d2) << 32) | (unsigned)m;
        if (key < lkey) lkey = key;
      }
    }
    if (lane == 0 && lkey != ~0ULL) atomicMin(&rkey[token], lkey);
  }
}

// ---------- kernel 5: gather f32 rows + zidx as f32 ----------
__global__ void gather_kernel(const float* __restrict__ tmp, const int* __restrict__ bestIdx,
                              const int* __restrict__ flag,
                              const unsigned long long* __restrict__ rkey,
                              float* __restrict__ out) {
  int token = blockIdx.x * 4 + (threadIdx.x >> 6);
  int lane = threadIdx.x & 63;
  int idx = flag[token] ? (int)(unsigned)(rkey[token] & 0xffffffffULL) : bestIdx[token];
  idx = idx < 0 ? 0 : (idx > NEMB - 1 ? NEMB - 1 : idx);
  const float4* src = (const float4*)(tmp + (size_t)idx * EMB) + lane * 2;
  float4* dst = (float4*)(out + (size_t)token * EMB) + lane * 2;
  dst[0] = src[0];
  dst[1] = src[1];
  if (lane == 0) out[(size_t)N_TOK * EMB + token] = (float)idx;
}

extern "C" void kernel_launch(void* const* d_in, const int* in_sizes, int n_in,
                              void* d_out, int out_size, void* d_ws, size_t ws_size,
                              hipStream_t stream) {
  const float* enc = (const float*)d_in[0];
  const float* tmp = (const float*)d_in[1];
  float* out = (float*)d_out;
  char* ws = (char*)d_ws;
  unsigned short* thi = (unsigned short*)ws;                 //  2,097,152 B
  unsigned short* ehi = (unsigned short*)(ws + 2097152);     // 16,777,216 B
  float* tsq      = (float*)(ws + 18874368);                 //      8,192 B
  float* esq      = (float*)(ws + 18882560);                 //     65,536 B
  unsigned long long* keyc = (unsigned long long*)(ws + 18948096); // 4,194,304 B
  unsigned* s2c   = (unsigned*)(ws + 23142400);              //  2,097,152 B
  int*   bestIdx  = (int*)  (ws + 25239552);                 //     65,536 B
  int*   flag     = (int*)  (ws + 25305088);                 //     65,536 B
  unsigned long long* rkey = (unsigned long long*)(ws + 25370624); // 131,072 B
  int*   wcount   = (int*)  (ws + 25501696);                 //         64 B
  int*   work     = (int*)  (ws + 25501760);                 //  2,097,152 B

  prep_kernel  <<<4608,      256, 0, stream>>>(tmp, enc, thi, tsq, ehi, esq, wcount);
  score_kernel <<<512,       512, 0, stream>>>(ehi, thi, tsq, keyc, s2c);
  merge_kernel <<<N_TOK/64,  64,  0, stream>>>(keyc, s2c, bestIdx, flag, work, wcount, rkey);
  refine_kernel<<<1024,      256, 0, stream>>>(enc, tmp, esq, tsq, work, wcount, rkey);
  gather_kernel<<<N_TOK/4,   256, 0, stream>>>(tmp, bestIdx, flag, rkey, out);
}

// Round 2
// 204.957 us; speedup vs baseline: 1.0919x; 1.0214x over previous
//
#include <hip/hip_runtime.h>
#include <stdint.h>

#define N_TOK  16384
#define EMB    512
#define NEMB   2048
#define NCHUNK 32            // 64 templates per chunk
#define CWIN   2.5e-4f       // ref-f32-grid + bf16 score-noise margin (passed R5-R7)
#define WCAP   524288

typedef __attribute__((ext_vector_type(8))) short s16x8;
typedef __attribute__((ext_vector_type(4))) float f32x4;

__device__ __forceinline__ unsigned short f2bf(float f) {   // RNE f32 -> bf16
  unsigned u = __float_as_uint(f);
  u += 0x7fffu + ((u >> 16) & 1u);
  return (unsigned short)(u >> 16);
}
// monotone f32 -> u32 (total order, NaN sorts above all reals)
__device__ __forceinline__ unsigned mapf(float f) {
  unsigned u = __float_as_uint(f);
  return (u >> 31) ? ~u : (u | 0x80000000u);
}
__device__ __forceinline__ float unmapf(unsigned u) {
  return __uint_as_float((u >> 31) ? (u & 0x7fffffffu) : ~u);
}

// DPP helpers: permute within 16-lane rows (all lanes active).
// quad_perm xor1 = 0xB1, xor2 = 0x4E; row_ror:4 = 0x124, row_ror:8 = 0x128.
template<int CTRL>
__device__ __forceinline__ float dppf(float x) {
  return __uint_as_float((unsigned)__builtin_amdgcn_update_dpp(
      0, (int)__float_as_uint(x), CTRL, 0xF, 0xF, true));
}
template<int CTRL>
__device__ __forceinline__ unsigned dppu(unsigned x) {
  return (unsigned)__builtin_amdgcn_update_dpp(0, (int)x, CTRL, 0xF, 0xF, true);
}

// numpy pairwise_sum emulation for sum(x*x) over 512 contiguous f32.
__device__ __forceinline__ float pairwise512_sq(const float* se, int lane) {
  int l = lane & 31;
  int b = l >> 3, j = l & 7;
  const float* base = se + b * 128 + j;
  float x = base[0];
  float r = __fmul_rn(x, x);
#pragma unroll
  for (int k = 1; k < 16; ++k) {
    float y = base[8 * k];
    r = __fadd_rn(r, __fmul_rn(y, y));
  }
  r = __fadd_rn(r, __shfl_xor(r, 1));
  r = __fadd_rn(r, __shfl_xor(r, 2));
  r = __fadd_rn(r, __shfl_xor(r, 4));
  r = __fadd_rn(r, __shfl_xor(r, 8));
  r = __fadd_rn(r, __shfl_xor(r, 16));
  return r;
}

// ---------- kernel 1: fused prep, 4 rows per block (wave per row) ----------
__global__ __launch_bounds__(256) void prep_kernel(
    const float* __restrict__ tmp, const float* __restrict__ enc,
    unsigned short* __restrict__ thi, float* __restrict__ tsq,
    unsigned short* __restrict__ ehi, float* __restrict__ esq,
    int* __restrict__ wcount) {
  __shared__ float se[4][EMB];
  int wv = threadIdx.x >> 6, lane = threadIdx.x & 63;
  int row = blockIdx.x * 4 + wv;                             // 18432 rows
  if (blockIdx.x == 0 && threadIdx.x == 0) *wcount = 0;
  bool isT = row < NEMB;
  const float* src = isT ? (tmp + (size_t)row * EMB)
                         : (enc + (size_t)(row - NEMB) * EMB);
  const float4* p = (const float4*)src + lane * 2;
  float4 v0 = p[0], v1 = p[1];
  float f[8] = {v0.x, v0.y, v0.z, v0.w, v1.x, v1.y, v1.z, v1.w};
  unsigned h[8];
#pragma unroll
  for (int i = 0; i < 8; ++i) { h[i] = f2bf(f[i]); se[wv][lane * 8 + i] = f[i]; }
  uint4 packed = { h[0] | (h[1] << 16), h[2] | (h[3] << 16),
                   h[4] | (h[5] << 16), h[6] | (h[7] << 16) };
  unsigned short* dsth = isT ? (thi + (size_t)row * EMB)
                             : (ehi + (size_t)(row - NEMB) * EMB);
  ((uint4*)dsth)[lane] = packed;
  __syncthreads();
  float s = pairwise512_sq(se[wv], lane);
  if (lane == 0) { if (isT) tsq[row] = s; else esq[row - NEMB] = s; }
}

// ---------- kernel 2: persistent 2-half 256x256 8-wave phased GEMM ----------
// grid 256 (1 block/CU): XCD-swizzled bid -> (tokb 0..63, nbq 0..3); each block
// processes template halves nb = nbq*2+half (half=0,1), 256 cols each.
// K-loop structure, LDS layout, swizzle, vmcnt ledger: identical to R1
// (verified, bank-conflict-free, scores bit-identical). New: half-1 prologue
// issued before half-0 epilogue (HBM latency hides under epilogue VALU);
// DPP-based in-register argmin epilogue (no LDS-pipe ops).
__global__ __launch_bounds__(512, 2) void score_kernel(
    const unsigned short* __restrict__ ehi, const unsigned short* __restrict__ thi,
    const float* __restrict__ tsq,
    unsigned long long* __restrict__ keyc, unsigned* __restrict__ s2c) {
  __shared__ __align__(16) char smem[131072];
  const int tid = threadIdx.x, w = tid >> 6, lane = tid & 63;
  const int q = lane >> 4, r = lane & 15;
  const int wr = w >> 2, wc = w & 3;               // 2M x 4N wave grid
  const int bid = (int)blockIdx.x;
  const int sw = (bid & 7) * 32 + (bid >> 3);      // bijective XCD swizzle (256%8==0)
  const int tokb = sw >> 2;                        // 0..63
  const int nbq  = sw & 3;                         // 0..3

  // ---- per-thread stage-source precompute (inverse swizzle of linear dest) ----
  const int c0 = tid, c1 = 512 + tid;
  const int L0 = (c0 * 16) ^ ((((c0 * 16) >> 9) & 1) << 5);
  const int L1 = (c1 * 16) ^ ((((c1 * 16) >> 9) & 1) << 5);
  const int row0 = L0 >> 6, ce0 = (L0 & 63) >> 1;
  const int row1 = L1 >> 6, ce1 = (L1 & 63) >> 1;
  const unsigned short* pa0 = ehi + (size_t)(tokb * 256 + row0) * EMB + ce0;
  const unsigned short* pa1 = ehi + (size_t)(tokb * 256 + row1) * EMB + ce1;
  const unsigned short* pb0 = thi + (size_t)(nbq * 512 + row0) * EMB + ce0;
  const unsigned short* pb1 = thi + (size_t)(nbq * 512 + row1) * EMB + ce1;

#define STAGE_A(ktp, kk) do {                                                     \
    char* lb_ = smem + ((((ktp) & 1) * 2 + (kk)) << 14) + (w << 10);              \
    __builtin_amdgcn_global_load_lds(                                             \
        (const __attribute__((address_space(1))) void*)(pa0 + (ktp) * 64 + (kk) * 32), \
        (__attribute__((address_space(3))) void*)lb_, 16, 0, 0);                  \
    __builtin_amdgcn_global_load_lds(                                             \
        (const __attribute__((address_space(1))) void*)(pa1 + (ktp) * 64 + (kk) * 32), \
        (__attribute__((address_space(3))) void*)(lb_ + 8192), 16, 0, 0);         \
  } while (0)
#define STAGE_B(ktp, kk) do {                                                     \
    char* lb_ = smem + 65536 + ((((ktp) & 1) * 2 + (kk)) << 14) + (w << 10);      \
    __builtin_amdgcn_global_load_lds(                                             \
        (const __attribute__((address_space(1))) void*)(pb0 + (ktp) * 64 + (kk) * 32), \
        (__attribute__((address_space(3))) void*)lb_, 16, 0, 0);                  \
    __builtin_amdgcn_global_load_lds(                                             \
        (const __attribute__((address_space(1))) void*)(pb1 + (ktp) * 64 + (kk) * 32), \
        (__attribute__((address_space(3))) void*)(lb_ + 8192), 16, 0, 0);         \
  } while (0)

  // ---- swizzled fragment-read offsets (within a 16 KB panel) ----
  int offA[8], offB[4];
#pragma unroll
  for (int m = 0; m < 8; ++m) {
    int P = (wr * 128 + m * 16 + r) * 64 + q * 16;
    offA[m] = P ^ (((P >> 9) & 1) << 5);
  }
#pragma unroll
  for (int n = 0; n < 4; ++n) {
    int P = (wc * 64 + n * 16 + r) * 64 + q * 16;
    offB[n] = P ^ (((P >> 9) & 1) << 5);
  }

#define LOADA(kkbase, mh)                                        \
    a0 = *(const s16x8*)(Ab_ + (kkbase) + offA[(mh) * 4 + 0]);   \
    a1 = *(const s16x8*)(Ab_ + (kkbase) + offA[(mh) * 4 + 1]);   \
    a2 = *(const s16x8*)(Ab_ + (kkbase) + offA[(mh) * 4 + 2]);   \
    a3 = *(const s16x8*)(Ab_ + (kkbase) + offA[(mh) * 4 + 3]);
#define LOADB(kkbase)                                            \
    bf4[0] = *(const s16x8*)(Bb_ + (kkbase) + offB[0]);          \
    bf4[1] = *(const s16x8*)(Bb_ + (kkbase) + offB[1]);          \
    bf4[2] = *(const s16x8*)(Bb_ + (kkbase) + offB[2]);          \
    bf4[3] = *(const s16x8*)(Bb_ + (kkbase) + offB[3]);
#define MFMA_HALF(mh)                                                              \
    __builtin_amdgcn_s_setprio(1);                                                 \
    _Pragma("unroll")                                                              \
    for (int n = 0; n < 4; ++n) {                                                  \
      acc[(mh) * 4 + 0][n] = __builtin_amdgcn_mfma_f32_16x16x32_bf16(a0, bf4[n], acc[(mh) * 4 + 0][n], 0, 0, 0); \
      acc[(mh) * 4 + 1][n] = __builtin_amdgcn_mfma_f32_16x16x32_bf16(a1, bf4[n], acc[(mh) * 4 + 1][n], 0, 0, 0); \
      acc[(mh) * 4 + 2][n] = __builtin_amdgcn_mfma_f32_16x16x32_bf16(a2, bf4[n], acc[(mh) * 4 + 2][n], 0, 0, 0); \
      acc[(mh) * 4 + 3][n] = __builtin_amdgcn_mfma_f32_16x16x32_bf16(a3, bf4[n], acc[(mh) * 4 + 3][n], 0, 0, 0); \
    }                                                                              \
    __builtin_amdgcn_s_setprio(0);

  f32x4 acc[8][4];

  // ---- half-0 prologue: kt0 all 4 panels + kt1 kk0 panels (units #1..#12) ----
  STAGE_A(0, 0); STAGE_B(0, 0); STAGE_A(0, 1); STAGE_B(0, 1); STAGE_A(1, 0); STAGE_B(1, 0);

#pragma unroll 1
  for (int half = 0; half < 2; ++half) {
    if (half == 0) { asm volatile("s_waitcnt vmcnt(8)" ::: "memory"); }
    else           { asm volatile("s_waitcnt vmcnt(0)" ::: "memory"); }
    __builtin_amdgcn_s_barrier();

#pragma unroll
    for (int ti = 0; ti < 8; ++ti)
#pragma unroll
      for (int j = 0; j < 4; ++j) acc[ti][j] = (f32x4){0.f, 0.f, 0.f, 0.f};

#pragma unroll
    for (int kt = 0; kt < 8; ++kt) {
      char* Ab_ = smem + ((kt & 1) * 2 << 14);
      char* Bb_ = smem + 65536 + ((kt & 1) * 2 << 14);
      s16x8 a0, a1, a2, a3, bf4[4];
      // -- g1: kk0, m0-3; stage A-kk1(kt+1)
      LOADA(0, 0); LOADB(0);
      if (kt + 1 < 8) STAGE_A(kt + 1, 1);
      __builtin_amdgcn_s_barrier();
      MFMA_HALF(0);
      __builtin_amdgcn_s_barrier();
      // -- g2: kk0, m4-7; stage B-kk1(kt+1); wait for kk1(kt)
      LOADA(0, 1);
      if (kt + 1 < 8) STAGE_B(kt + 1, 1);
      __builtin_amdgcn_s_barrier();
      MFMA_HALF(1);
      if (kt < 7) { asm volatile("s_waitcnt vmcnt(8)" ::: "memory"); }
      else        { asm volatile("s_waitcnt vmcnt(0)" ::: "memory"); }
      __builtin_amdgcn_s_barrier();
      // -- g3: kk1, m0-3; stage A-kk0(kt+2)
      LOADA(16384, 0); LOADB(16384);
      if (kt + 2 < 8) STAGE_A(kt + 2, 0);
      __builtin_amdgcn_s_barrier();
      MFMA_HALF(0);
      __builtin_amdgcn_s_barrier();
      // -- g4: kk1, m4-7; stage B-kk0(kt+2); wait for kk0(kt+1)
      LOADA(16384, 1);
      if (kt + 2 < 8) STAGE_B(kt + 2, 0);
      __builtin_amdgcn_s_barrier();
      MFMA_HALF(1);
      if (kt < 6)       { asm volatile("s_waitcnt vmcnt(8)" ::: "memory"); }
      else if (kt == 6) { asm volatile("s_waitcnt vmcnt(4)" ::: "memory"); }
      __builtin_amdgcn_s_barrier();
    }

    // ---- issue half-1 prologue now: HBM latency hides under the epilogue.
    // Safe: targets buf0 kk0/kk1 + buf1 kk0, whose last reads completed before
    // the kt6-g4 / kt7-g2 barriers above.
    if (half == 0) {
      pb0 += (size_t)256 * EMB; pb1 += (size_t)256 * EMB;
      STAGE_A(0, 0); STAGE_B(0, 0); STAGE_A(0, 1); STAGE_B(0, 1); STAGE_A(1, 0); STAGE_B(1, 0);
    }

    // ---- epilogue: DPP in-register argmin (no LDS). Wave (wr,wc) owns
    // tokens wr*128..+127 of chunk nb*4+wc; reduce over the 16-lane row (r).
    {
      const int nb = nbq * 2 + half;
      const int chunk = nb * 4 + wc;
      const int nbase = nb * 256 + wc * 64;
      const float tq0 = tsq[nbase + r], tq1 = tsq[nbase + 16 + r],
                  tq2 = tsq[nbase + 32 + r], tq3 = tsq[nbase + 48 + r];
#define FOLD(CTRL) { float os_ = dppf<CTRL>(sb), os2_ = dppf<CTRL>(s2f);        \
      float mx_ = fmaxf(sb, os_);                                               \
      s2f = fminf(fminf(s2f, os2_), mx_); sb = fminf(sb, os_); }
#define FOLDL(CTRL) { unsigned ol_ = dppu<CTRL>(li); li = li < ol_ ? li : ol_; }
#pragma unroll
      for (int m = 0; m < 8; ++m) {
        unsigned long long kk[4]; unsigned ss[4];
#pragma unroll
        for (int i = 0; i < 4; ++i) {
          float s0 = fmaf(-2.f, acc[m][0][i], tq0);   // == tq - fl(2*acc): exact scale
          float s1 = fmaf(-2.f, acc[m][1][i], tq1);
          float s2v = fmaf(-2.f, acc[m][2][i], tq2);
          float s3 = fmaf(-2.f, acc[m][3][i], tq3);
          // within-lane min + exact second-of-4 (dup-safe)
          float n01 = fminf(s0, s1), X01 = fmaxf(s0, s1);
          float n23 = fminf(s2v, s3), X23 = fmaxf(s2v, s3);
          float sb = fminf(n01, n23);
          float s2f = fminf(fminf(X01, X23), fmaxf(n01, n23));
          // row fold: (min, second) pair-merge, cyclic so all lanes get result
          FOLD(0xB1) FOLD(0x4E) FOLD(0x124) FOLD(0x128)
          // exact lexicographic index recovery: lowest (n,r) matching row-min
          unsigned li = 0xFFFFFFFFu;
          li = (s3  == sb) ? (unsigned)(48 + r) : li;
          li = (s2v == sb) ? (unsigned)(32 + r) : li;
          li = (s1  == sb) ? (unsigned)(16 + r) : li;
          li = (s0  == sb) ? (unsigned)(r)      : li;
          FOLDL(0xB1) FOLDL(0x4E) FOLDL(0x124) FOLDL(0x128)
          kk[i] = ((unsigned long long)mapf(sb) << 32) | (unsigned)(nbase + (int)li);
          ss[i] = mapf(s2f);
        }
        if (r == 0) {
          size_t base = (size_t)chunk * N_TOK +
                        (size_t)(tokb * 256 + wr * 128 + m * 16 + q * 4);
          ((ulonglong2*)&keyc[base])[0] = make_ulonglong2(kk[0], kk[1]);
          ((ulonglong2*)&keyc[base])[1] = make_ulonglong2(kk[2], kk[3]);
          *(uint4*)&s2c[base] = make_uint4(ss[0], ss[1], ss[2], ss[3]);
        }
      }
#undef FOLD
#undef FOLDL
    }
  }
#undef STAGE_A
#undef STAGE_B
#undef LOADA
#undef LOADB
#undef MFMA_HALF
}

// ---------- kernel 3: 32-way key merge, flag, worklist; inits rkey ----------
__global__ __launch_bounds__(256) void merge_kernel(
    const unsigned long long* __restrict__ keyc, const unsigned* __restrict__ s2c,
    int* __restrict__ bestIdx, int* __restrict__ flag, int* __restrict__ work,
    int* __restrict__ wcount, unsigned long long* __restrict__ rkey) {
  int t = blockIdx.x * 256 + threadIdx.x;
  if (t >= N_TOK) return;
  rkey[t] = ~0ULL;
  unsigned long long K = ~0ULL; unsigned S = 0xffffffffu;
  for (int c = 0; c < NCHUNK; ++c) {
    unsigned long long k = keyc[(size_t)c * N_TOK + t];
    unsigned s2 = s2c[(size_t)c * N_TOK + t];
    if (k < K) { unsigned o = (unsigned)(K >> 32); S = o < S ? o : S; K = k; }
    else { unsigned o = (unsigned)(k >> 32); S = o < S ? o : S; }
    S = s2 < S ? s2 : S;
  }
  float best_f   = unmapf((unsigned)(K >> 32));
  float second_f = unmapf(S);
  int idx = (int)(unsigned)(K & 0xffffffffu);
  bestIdx[t] = idx;
  bool ok = (second_f - best_f >= CWIN) && (idx >= 0) && (idx < NEMB) && (best_f == best_f);
  flag[t] = ok ? 0 : 1;
  if (!ok) {
    bool nanCase = !(best_f == best_f);
    float limit = best_f + CWIN;
    for (int c = 0; c < NCHUNK; ++c) {
      float cf = unmapf((unsigned)(keyc[(size_t)c * N_TOK + t] >> 32));
      if (nanCase || !(cf > limit)) {               // NaN-safe candidate test
        int pos = atomicAdd(wcount, 1);
        if (pos < WCAP) work[pos] = t * NCHUNK + c;
      }
    }
  }
}

// ---------- kernel 4: f32-emulated rescan, 16 lanes per template ----------
// 4 templates per wave in parallel (group g = lane>>4); double accumulation is
// associativity-equivalent to the previous 64-lane tree (rounds once to f32).
__global__ __launch_bounds__(256) void refine_kernel(
    const float* __restrict__ enc, const float* __restrict__ tmp,
    const float* __restrict__ esq, const float* __restrict__ tsq,
    const int* __restrict__ work, const int* __restrict__ wcount,
    unsigned long long* __restrict__ rkey) {
  int total = *wcount; if (total > WCAP) total = WCAP;
  __shared__ float se[EMB];
  const int wv = threadIdx.x >> 6, lane = threadIdx.x & 63;
  const int g = lane >> 4, l16 = lane & 15;
  for (int p = blockIdx.x; p < total; p += gridDim.x) {
    __syncthreads();
    int item = work[p];
    int token = item / NCHUNK, c = item % NCHUNK;
    const float4* erow = (const float4*)(enc + (size_t)token * EMB);
    for (int i = threadIdx.x; i < 128; i += 256) ((float4*)se)[i] = erow[i];
    __syncthreads();
    float e2 = esq[token];
    unsigned long long lkey = ~0ULL;
#pragma unroll
    for (int j = 0; j < 4; ++j) {
      int m = c * 64 + wv * 16 + j * 4 + g;
      const float4* trow = (const float4*)(tmp + (size_t)m * EMB);
      double s = 0.0;
#pragma unroll
      for (int k = 0; k < 8; ++k) {
        float4 a = trow[l16 + 16 * k];
        float4 b = ((const float4*)se)[l16 + 16 * k];
        s += (double)a.x * b.x + (double)a.y * b.y
           + (double)a.z * b.z + (double)a.w * b.w;
      }
      s += __shfl_xor(s, 1); s += __shfl_xor(s, 2);
      s += __shfl_xor(s, 4); s += __shfl_xor(s, 8);
      if (l16 == 0) {
        float M  = (float)s;
        float d1 = __fadd_rn(e2, -__fmul_rn(2.0f, M));
        float d2 = __fadd_rn(d1, tsq[m]);            // full dist >= 0: bits monotone
        unsigned long long key =
            ((unsigned long long)__float_as_uint(d2) << 32) | (unsigned)m;
        if (key < lkey) lkey = key;
      }
    }
    if (l16 == 0 && lkey != ~0ULL) atomicMin(&rkey[token], lkey);
  }
}

// ---------- kernel 5: gather f32 rows + zidx as f32 ----------
__global__ void gather_kernel(const float* __restrict__ tmp, const int* __restrict__ bestIdx,
                              const int* __restrict__ flag,
                              const unsigned long long* __restrict__ rkey,
                              float* __restrict__ out) {
  int token = blockIdx.x * 4 + (threadIdx.x >> 6);
  int lane = threadIdx.x & 63;
  int idx = flag[token] ? (int)(unsigned)(rkey[token] & 0xffffffffULL) : bestIdx[token];
  idx = idx < 0 ? 0 : (idx > NEMB - 1 ? NEMB - 1 : idx);
  const float4* src = (const float4*)(tmp + (size_t)idx * EMB) + lane * 2;
  float4* dst = (float4*)(out + (size_t)token * EMB) + lane * 2;
  dst[0] = src[0];
  dst[1] = src[1];
  if (lane == 0) out[(size_t)N_TOK * EMB + token] = (float)idx;
}

extern "C" void kernel_launch(void* const* d_in, const int* in_sizes, int n_in,
                              void* d_out, int out_size, void* d_ws, size_t ws_size,
                              hipStream_t stream) {
  const float* enc = (const float*)d_in[0];
  const float* tmp = (const float*)d_in[1];
  float* out = (float*)d_out;
  char* ws = (char*)d_ws;
  unsigned short* thi = (unsigned short*)ws;                 //  2,097,152 B
  unsigned short* ehi = (unsigned short*)(ws + 2097152);     // 16,777,216 B
  float* tsq      = (float*)(ws + 18874368);                 //      8,192 B
  float* esq      = (float*)(ws + 18882560);                 //     65,536 B
  unsigned long long* keyc = (unsigned long long*)(ws + 18948096); // 4,194,304 B
  unsigned* s2c   = (unsigned*)(ws + 23142400);              //  2,097,152 B
  int*   bestIdx  = (int*)  (ws + 25239552);                 //     65,536 B
  int*   flag     = (int*)  (ws + 25305088);                 //     65,536 B
  unsigned long long* rkey = (unsigned long long*)(ws + 25370624); // 131,072 B
  int*   wcount   = (int*)  (ws + 25501696);                 //         64 B
  int*   work     = (int*)  (ws + 25501760);                 //  2,097,152 B

  prep_kernel  <<<4608,      256, 0, stream>>>(tmp, enc, thi, tsq, ehi, esq, wcount);
  score_kernel <<<256,       512, 0, stream>>>(ehi, thi, tsq, keyc, s2c);
  merge_kernel <<<N_TOK/256, 256, 0, stream>>>(keyc, s2c, bestIdx, flag, work, wcount, rkey);
  refine_kernel<<<1024,      256, 0, stream>>>(enc, tmp, esq, tsq, work, wcount, rkey);
  gather_kernel<<<N_TOK/4,   256, 0, stream>>>(tmp, bestIdx, flag, rkey, out);
}

// Round 3
// 188.781 us; speedup vs baseline: 1.1854x; 1.0857x over previous
//
#include <hip/hip_runtime.h>
#include <stdint.h>

#define N_TOK  16384
#define EMB    512
#define NEMB   2048
#define NCHUNK 32            // 64 templates per chunk
#define CWIN   2.5e-4f       // ref-f32-grid + bf16 score-noise margin (passed R5-R7)
#define WCAP   524288

typedef __attribute__((ext_vector_type(8))) short s16x8;
typedef __attribute__((ext_vector_type(4))) float f32x4;

__device__ __forceinline__ unsigned short f2bf(float f) {   // RNE f32 -> bf16
  unsigned u = __float_as_uint(f);
  u += 0x7fffu + ((u >> 16) & 1u);
  return (unsigned short)(u >> 16);
}
// monotone f32 -> u32 (total order, NaN sorts above all reals)
__device__ __forceinline__ unsigned mapf(float f) {
  unsigned u = __float_as_uint(f);
  return (u >> 31) ? ~u : (u | 0x80000000u);
}
__device__ __forceinline__ float unmapf(unsigned u) {
  return __uint_as_float((u >> 31) ? (u & 0x7fffffffu) : ~u);
}

// numpy pairwise_sum emulation for sum(x*x) over 512 contiguous f32.
__device__ __forceinline__ float pairwise512_sq(const float* se, int lane) {
  int l = lane & 31;
  int b = l >> 3, j = l & 7;
  const float* base = se + b * 128 + j;
  float x = base[0];
  float r = __fmul_rn(x, x);
#pragma unroll
  for (int k = 1; k < 16; ++k) {
    float y = base[8 * k];
    r = __fadd_rn(r, __fmul_rn(y, y));
  }
  r = __fadd_rn(r, __shfl_xor(r, 1));
  r = __fadd_rn(r, __shfl_xor(r, 2));
  r = __fadd_rn(r, __shfl_xor(r, 4));
  r = __fadd_rn(r, __shfl_xor(r, 8));
  r = __fadd_rn(r, __shfl_xor(r, 16));
  return r;
}

// ---------- kernel 1: fused prep, 4 rows per block (wave per row) ----------
__global__ __launch_bounds__(256) void prep_kernel(
    const float* __restrict__ tmp, const float* __restrict__ enc,
    unsigned short* __restrict__ thi, float* __restrict__ tsq,
    unsigned short* __restrict__ ehi, float* __restrict__ esq,
    int* __restrict__ wcount) {
  __shared__ float se[4][EMB];
  int wv = threadIdx.x >> 6, lane = threadIdx.x & 63;
  int row = blockIdx.x * 4 + wv;                             // 18432 rows
  if (blockIdx.x == 0 && threadIdx.x == 0) *wcount = 0;
  bool isT = row < NEMB;
  const float* src = isT ? (tmp + (size_t)row * EMB)
                         : (enc + (size_t)(row - NEMB) * EMB);
  const float4* p = (const float4*)src + lane * 2;
  float4 v0 = p[0], v1 = p[1];
  float f[8] = {v0.x, v0.y, v0.z, v0.w, v1.x, v1.y, v1.z, v1.w};
  unsigned h[8];
#pragma unroll
  for (int i = 0; i < 8; ++i) { h[i] = f2bf(f[i]); se[wv][lane * 8 + i] = f[i]; }
  uint4 packed = { h[0] | (h[1] << 16), h[2] | (h[3] << 16),
                   h[4] | (h[5] << 16), h[6] | (h[7] << 16) };
  unsigned short* dsth = isT ? (thi + (size_t)row * EMB)
                             : (ehi + (size_t)(row - NEMB) * EMB);
  ((uint4*)dsth)[lane] = packed;
  __syncthreads();
  float s = pairwise512_sq(se[wv], lane);
  if (lane == 0) { if (isT) tsq[row] = s; else esq[row - NEMB] = s; }
}

// ---------- kernel 2: 256x256-tile 8-wave phased GEMM (T2+T3+T4+T5) ----------
// EXACT R1 structure (57 us, VGPR 112, 0 bank conflicts, no spill). Single
// change: bid -> (tokb, nb) remap for XCD L2 locality. XCD x (= bid%8,
// round-robin heuristic) gets tokb in {8x..8x+7} across its 2 block-rounds,
// and all 8 nb for a tokb land on the same XCD: ehi panels (2 MB) + thi
// (2 MB) both L2-resident -> ideal fetch ~34 MB (was 67.8 MB).
// K = 512 = 8 K-tiles of BK=64; each K-tile = two 32-wide kk panels.
// LDS 128 KiB, st_16x32 swizzle via inverse-swizzled global source (linear
// global_load_lds dest) + swizzled ds_read. vmcnt ledger: waits of 8 (steady),
// 4/0 (drain) before barriers; never drains mid-loop.
// MFMA order per acc element: kt ascending, kk0 then kk1 -> scores
// BIT-IDENTICAL to R1/R2; downstream CWIN/refine logic unchanged.
__global__ __launch_bounds__(512, 2) void score_kernel(
    const unsigned short* __restrict__ ehi, const unsigned short* __restrict__ thi,
    const float* __restrict__ tsq,
    unsigned long long* __restrict__ keyc, unsigned* __restrict__ s2c) {
  __shared__ __align__(16) char smem[131072];
  const int tid = threadIdx.x, w = tid >> 6, lane = tid & 63;
  const int q = lane >> 4, r = lane & 15;
  const int wr = w >> 2, wc = w & 3;               // 2M x 4N wave grid
  const int bid = (int)blockIdx.x;
  const int x   = bid & 7;                         // XCD (round-robin heuristic)
  const int j   = bid >> 3;                        // 0..63
  const int rho = j >> 5;                          // block-round 0/1
  const int cc  = j & 31;
  const int tokb = x * 8 + rho * 4 + (cc >> 3);    // 0..63
  const int nb   = cc & 7;                         // 0..7

  // ---- per-thread stage-source precompute (inverse swizzle of linear dest) ----
  const int c0 = tid, c1 = 512 + tid;
  const int L0 = (c0 * 16) ^ ((((c0 * 16) >> 9) & 1) << 5);
  const int L1 = (c1 * 16) ^ ((((c1 * 16) >> 9) & 1) << 5);
  const int row0 = L0 >> 6, ce0 = (L0 & 63) >> 1;
  const int row1 = L1 >> 6, ce1 = (L1 & 63) >> 1;
  const unsigned short* pa0 = ehi + (size_t)(tokb * 256 + row0) * EMB + ce0;
  const unsigned short* pa1 = ehi + (size_t)(tokb * 256 + row1) * EMB + ce1;
  const unsigned short* pb0 = thi + (size_t)(nb  * 256 + row0) * EMB + ce0;
  const unsigned short* pb1 = thi + (size_t)(nb  * 256 + row1) * EMB + ce1;

#define STAGE_A(ktp, kk) do {                                                     \
    char* lb_ = smem + ((((ktp) & 1) * 2 + (kk)) << 14) + (w << 10);              \
    __builtin_amdgcn_global_load_lds(                                             \
        (const __attribute__((address_space(1))) void*)(pa0 + (ktp) * 64 + (kk) * 32), \
        (__attribute__((address_space(3))) void*)lb_, 16, 0, 0);                  \
    __builtin_amdgcn_global_load_lds(                                             \
        (const __attribute__((address_space(1))) void*)(pa1 + (ktp) * 64 + (kk) * 32), \
        (__attribute__((address_space(3))) void*)(lb_ + 8192), 16, 0, 0);         \
  } while (0)
#define STAGE_B(ktp, kk) do {                                                     \
    char* lb_ = smem + 65536 + ((((ktp) & 1) * 2 + (kk)) << 14) + (w << 10);      \
    __builtin_amdgcn_global_load_lds(                                             \
        (const __attribute__((address_space(1))) void*)(pb0 + (ktp) * 64 + (kk) * 32), \
        (__attribute__((address_space(3))) void*)lb_, 16, 0, 0);                  \
    __builtin_amdgcn_global_load_lds(                                             \
        (const __attribute__((address_space(1))) void*)(pb1 + (ktp) * 64 + (kk) * 32), \
        (__attribute__((address_space(3))) void*)(lb_ + 8192), 16, 0, 0);         \
  } while (0)

  // ---- swizzled fragment-read offsets (within a 16 KB panel) ----
  int offA[8], offB[4];
#pragma unroll
  for (int m = 0; m < 8; ++m) {
    int P = (wr * 128 + m * 16 + r) * 64 + q * 16;
    offA[m] = P ^ (((P >> 9) & 1) << 5);
  }
#pragma unroll
  for (int n = 0; n < 4; ++n) {
    int P = (wc * 64 + n * 16 + r) * 64 + q * 16;
    offB[n] = P ^ (((P >> 9) & 1) << 5);
  }

  f32x4 acc[8][4];
#pragma unroll
  for (int m = 0; m < 8; ++m)
#pragma unroll
    for (int n = 0; n < 4; ++n) acc[m][n] = (f32x4){0.f, 0.f, 0.f, 0.f};

  // ---- prologue: kt0 all 4 panels + kt1 kk0 panels (units #1..#6) ----
  STAGE_A(0, 0); STAGE_B(0, 0); STAGE_A(0, 1); STAGE_B(0, 1); STAGE_A(1, 0); STAGE_B(1, 0);
  asm volatile("s_waitcnt vmcnt(8)" ::: "memory");   // units 1,2 (kk0 of kt0) landed
  __builtin_amdgcn_s_barrier();

#define LOADA(kkbase, mh)                                        \
    a0 = *(const s16x8*)(Ab_ + (kkbase) + offA[(mh) * 4 + 0]);   \
    a1 = *(const s16x8*)(Ab_ + (kkbase) + offA[(mh) * 4 + 1]);   \
    a2 = *(const s16x8*)(Ab_ + (kkbase) + offA[(mh) * 4 + 2]);   \
    a3 = *(const s16x8*)(Ab_ + (kkbase) + offA[(mh) * 4 + 3]);
#define LOADB(kkbase)                                            \
    bf4[0] = *(const s16x8*)(Bb_ + (kkbase) + offB[0]);          \
    bf4[1] = *(const s16x8*)(Bb_ + (kkbase) + offB[1]);          \
    bf4[2] = *(const s16x8*)(Bb_ + (kkbase) + offB[2]);          \
    bf4[3] = *(const s16x8*)(Bb_ + (kkbase) + offB[3]);
#define MFMA_HALF(mh)                                                              \
    __builtin_amdgcn_s_setprio(1);                                                 \
    _Pragma("unroll")                                                              \
    for (int n = 0; n < 4; ++n) {                                                  \
      acc[(mh) * 4 + 0][n] = __builtin_amdgcn_mfma_f32_16x16x32_bf16(a0, bf4[n], acc[(mh) * 4 + 0][n], 0, 0, 0); \
      acc[(mh) * 4 + 1][n] = __builtin_amdgcn_mfma_f32_16x16x32_bf16(a1, bf4[n], acc[(mh) * 4 + 1][n], 0, 0, 0); \
      acc[(mh) * 4 + 2][n] = __builtin_amdgcn_mfma_f32_16x16x32_bf16(a2, bf4[n], acc[(mh) * 4 + 2][n], 0, 0, 0); \
      acc[(mh) * 4 + 3][n] = __builtin_amdgcn_mfma_f32_16x16x32_bf16(a3, bf4[n], acc[(mh) * 4 + 3][n], 0, 0, 0); \
    }                                                                              \
    __builtin_amdgcn_s_setprio(0);

#pragma unroll
  for (int kt = 0; kt < 8; ++kt) {
    char* Ab_ = smem + ((kt & 1) * 2 << 14);
    char* Bb_ = smem + 65536 + ((kt & 1) * 2 << 14);
    s16x8 a0, a1, a2, a3, bf4[4];
    // -- g1: kk0, m0-3; stage A-kk1(kt+1)
    LOADA(0, 0); LOADB(0);
    if (kt + 1 < 8) STAGE_A(kt + 1, 1);
    __builtin_amdgcn_s_barrier();
    MFMA_HALF(0);
    __builtin_amdgcn_s_barrier();
    // -- g2: kk0, m4-7; stage B-kk1(kt+1); wait for kk1(kt)
    LOADA(0, 1);
    if (kt + 1 < 8) STAGE_B(kt + 1, 1);
    __builtin_amdgcn_s_barrier();
    MFMA_HALF(1);
    if (kt < 7) { asm volatile("s_waitcnt vmcnt(8)" ::: "memory"); }
    else        { asm volatile("s_waitcnt vmcnt(0)" ::: "memory"); }
    __builtin_amdgcn_s_barrier();
    // -- g3: kk1, m0-3; stage A-kk0(kt+2)
    LOADA(16384, 0); LOADB(16384);
    if (kt + 2 < 8) STAGE_A(kt + 2, 0);
    __builtin_amdgcn_s_barrier();
    MFMA_HALF(0);
    __builtin_amdgcn_s_barrier();
    // -- g4: kk1, m4-7; stage B-kk0(kt+2); wait for kk0(kt+1)
    LOADA(16384, 1);
    if (kt + 2 < 8) STAGE_B(kt + 2, 0);
    __builtin_amdgcn_s_barrier();
    MFMA_HALF(1);
    if (kt < 6)       { asm volatile("s_waitcnt vmcnt(8)" ::: "memory"); }
    else if (kt == 6) { asm volatile("s_waitcnt vmcnt(4)" ::: "memory"); }
    __builtin_amdgcn_s_barrier();
  }

  // ---- epilogue: in-register argmin; wave (wr,wc) owns tokens wr*128..+127
  // of chunk nb*4+wc. Butterfly over r (16 template cols per fragment).
  const int chunk = nb * 4 + wc;
  const int nbase = nb * 256 + wc * 64;
  float tq[4];
#pragma unroll
  for (int n = 0; n < 4; ++n) tq[n] = tsq[nbase + n * 16 + r];
#pragma unroll
  for (int m = 0; m < 8; ++m) {
#pragma unroll
    for (int i = 0; i < 4; ++i) {
      unsigned long long k1 = ~0ULL; unsigned s2m = 0xffffffffu;
#pragma unroll
      for (int n = 0; n < 4; ++n) {                 // n ascending = template ascending
        float s = tq[n] - 2.0f * acc[m][n][i];
        unsigned sm = mapf(s);
        unsigned long long k =
            ((unsigned long long)sm << 32) | (unsigned)(nbase + n * 16 + r);
        if (k < k1) { unsigned o = (unsigned)(k1 >> 32); s2m = o < s2m ? o : s2m; k1 = k; }
        else s2m = sm < s2m ? sm : s2m;
      }
#pragma unroll
      for (int mask = 1; mask < 16; mask <<= 1) {
        unsigned long long ok = __shfl_xor(k1, mask);
        unsigned os = __shfl_xor(s2m, mask);
        if (ok < k1) { unsigned o = (unsigned)(k1 >> 32); s2m = o < s2m ? o : s2m; k1 = ok; }
        else { unsigned o = (unsigned)(ok >> 32); s2m = o < s2m ? o : s2m; }
        s2m = os < s2m ? os : s2m;
      }
      if (r == 0) {
        int token = tokb * 256 + wr * 128 + m * 16 + q * 4 + i;
        keyc[(size_t)chunk * N_TOK + token] = k1;
        s2c [(size_t)chunk * N_TOK + token] = s2m;
      }
    }
  }
#undef STAGE_A
#undef STAGE_B
#undef LOADA
#undef LOADB
#undef MFMA_HALF
}

// ---------- kernel 3: 32-way key merge, flag, worklist; inits rkey ----------
__global__ __launch_bounds__(256) void merge_kernel(
    const unsigned long long* __restrict__ keyc, const unsigned* __restrict__ s2c,
    int* __restrict__ bestIdx, int* __restrict__ flag, int* __restrict__ work,
    int* __restrict__ wcount, unsigned long long* __restrict__ rkey) {
  int t = blockIdx.x * 256 + threadIdx.x;
  if (t >= N_TOK) return;
  rkey[t] = ~0ULL;
  unsigned long long K = ~0ULL; unsigned S = 0xffffffffu;
  for (int c = 0; c < NCHUNK; ++c) {
    unsigned long long k = keyc[(size_t)c * N_TOK + t];
    unsigned s2 = s2c[(size_t)c * N_TOK + t];
    if (k < K) { unsigned o = (unsigned)(K >> 32); S = o < S ? o : S; K = k; }
    else { unsigned o = (unsigned)(k >> 32); S = o < S ? o : S; }
    S = s2 < S ? s2 : S;
  }
  float best_f   = unmapf((unsigned)(K >> 32));
  float second_f = unmapf(S);
  int idx = (int)(unsigned)(K & 0xffffffffu);
  bestIdx[t] = idx;
  bool ok = (second_f - best_f >= CWIN) && (idx >= 0) && (idx < NEMB) && (best_f == best_f);
  flag[t] = ok ? 0 : 1;
  if (!ok) {
    bool nanCase = !(best_f == best_f);
    float limit = best_f + CWIN;
    for (int c = 0; c < NCHUNK; ++c) {
      float cf = unmapf((unsigned)(keyc[(size_t)c * N_TOK + t] >> 32));
      if (nanCase || !(cf > limit)) {               // NaN-safe candidate test
        int pos = atomicAdd(wcount, 1);
        if (pos < WCAP) work[pos] = t * NCHUNK + c;
      }
    }
  }
}

// ---------- kernel 4: f32-emulated rescan, 16 lanes per template ----------
// 4 templates per wave in parallel (group g = lane>>4); double accumulation is
// associativity-equivalent to the previous 64-lane tree (rounds once to f32).
__global__ __launch_bounds__(256) void refine_kernel(
    const float* __restrict__ enc, const float* __restrict__ tmp,
    const float* __restrict__ esq, const float* __restrict__ tsq,
    const int* __restrict__ work, const int* __restrict__ wcount,
    unsigned long long* __restrict__ rkey) {
  int total = *wcount; if (total > WCAP) total = WCAP;
  __shared__ float se[EMB];
  const int wv = threadIdx.x >> 6, lane = threadIdx.x & 63;
  const int g = lane >> 4, l16 = lane & 15;
  for (int p = blockIdx.x; p < total; p += gridDim.x) {
    __syncthreads();
    int item = work[p];
    int token = item / NCHUNK, c = item % NCHUNK;
    const float4* erow = (const float4*)(enc + (size_t)token * EMB);
    for (int i = threadIdx.x; i < 128; i += 256) ((float4*)se)[i] = erow[i];
    __syncthreads();
    float e2 = esq[token];
    unsigned long long lkey = ~0ULL;
#pragma unroll
    for (int j = 0; j < 4; ++j) {
      int m = c * 64 + wv * 16 + j * 4 + g;
      const float4* trow = (const float4*)(tmp + (size_t)m * EMB);
      double s = 0.0;
#pragma unroll
      for (int k = 0; k < 8; ++k) {
        float4 a = trow[l16 + 16 * k];
        float4 b = ((const float4*)se)[l16 + 16 * k];
        s += (double)a.x * b.x + (double)a.y * b.y
           + (double)a.z * b.z + (double)a.w * b.w;
      }
      s += __shfl_xor(s, 1); s += __shfl_xor(s, 2);
      s += __shfl_xor(s, 4); s += __shfl_xor(s, 8);
      if (l16 == 0) {
        float M  = (float)s;
        float d1 = __fadd_rn(e2, -__fmul_rn(2.0f, M));
        float d2 = __fadd_rn(d1, tsq[m]);            // full dist >= 0: bits monotone
        unsigned long long key =
            ((unsigned long long)__float_as_uint(d2) << 32) | (unsigned)m;
        if (key < lkey) lkey = key;
      }
    }
    if (l16 == 0 && lkey != ~0ULL) atomicMin(&rkey[token], lkey);
  }
}

// ---------- kernel 5: gather f32 rows + zidx as f32 ----------
__global__ void gather_kernel(const float* __restrict__ tmp, const int* __restrict__ bestIdx,
                              const int* __restrict__ flag,
                              const unsigned long long* __restrict__ rkey,
                              float* __restrict__ out) {
  int token = blockIdx.x * 4 + (threadIdx.x >> 6);
  int lane = threadIdx.x & 63;
  int idx = flag[token] ? (int)(unsigned)(rkey[token] & 0xffffffffULL) : bestIdx[token];
  idx = idx < 0 ? 0 : (idx > NEMB - 1 ? NEMB - 1 : idx);
  const float4* src = (const float4*)(tmp + (size_t)idx * EMB) + lane * 2;
  float4* dst = (float4*)(out + (size_t)token * EMB) + lane * 2;
  dst[0] = src[0];
  dst[1] = src[1];
  if (lane == 0) out[(size_t)N_TOK * EMB + token] = (float)idx;
}

extern "C" void kernel_launch(void* const* d_in, const int* in_sizes, int n_in,
                              void* d_out, int out_size, void* d_ws, size_t ws_size,
                              hipStream_t stream) {
  const float* enc = (const float*)d_in[0];
  const float* tmp = (const float*)d_in[1];
  float* out = (float*)d_out;
  char* ws = (char*)d_ws;
  unsigned short* thi = (unsigned short*)ws;                 //  2,097,152 B
  unsigned short* ehi = (unsigned short*)(ws + 2097152);     // 16,777,216 B
  float* tsq      = (float*)(ws + 18874368);                 //      8,192 B
  float* esq      = (float*)(ws + 18882560);                 //     65,536 B
  unsigned long long* keyc = (unsigned long long*)(ws + 18948096); // 4,194,304 B
  unsigned* s2c   = (unsigned*)(ws + 23142400);              //  2,097,152 B
  int*   bestIdx  = (int*)  (ws + 25239552);                 //     65,536 B
  int*   flag     = (int*)  (ws + 25305088);                 //     65,536 B
  unsigned long long* rkey = (unsigned long long*)(ws + 25370624); // 131,072 B
  int*   wcount   = (int*)  (ws + 25501696);                 //         64 B
  int*   work     = (int*)  (ws + 25501760);                 //  2,097,152 B

  prep_kernel  <<<4608,      256, 0, stream>>>(tmp, enc, thi, tsq, ehi, esq, wcount);
  score_kernel <<<512,       512, 0, stream>>>(ehi, thi, tsq, keyc, s2c);
  merge_kernel <<<N_TOK/256, 256, 0, stream>>>(keyc, s2c, bestIdx, flag, work, wcount, rkey);
  refine_kernel<<<1024,      256, 0, stream>>>(enc, tmp, esq, tsq, work, wcount, rkey);
  gather_kernel<<<N_TOK/4,   256, 0, stream>>>(tmp, bestIdx, flag, rkey, out);
}